// Round 9
// baseline (41.934 us; speedup 1.0000x reference)
//
#include <hip/hip_runtime.h>

#define BB 2
#define NN1 512
#define NN2 512
#define DD 128

typedef float v4f __attribute__((ext_vector_type(4)));

// ---- Trans-free GELU via degree-9 Chebyshev fit (verified R5-R8: absmax 0.0156)
struct GeluPoly {
    float p[10];
    constexpr GeluPoly() : p{} {
        const int N = 10;
        const double PI = 3.14159265358979323846;
        double fv[10] = {};
        double xv[10] = {};
        for (int j = 0; j < N; ++j) {
            double th = PI * (j + 0.5) / N;
            double cth = 1.0, term = 1.0, t2 = th * th;
            for (int k = 1; k <= 30; ++k) {
                term *= -t2 / ((2.0 * k - 1.0) * (2.0 * k));
                cth += term;
            }
            xv[j] = cth;
            double t = 4.5 * (cth + 1.0);
            double s = t > 1.0 ? t : 1.0;
            for (int it = 0; it < 64; ++it) s = 0.5 * (s + t / s);
            double x = s * 0.70710678118654752440;
            double esum = 0.0, pw = x, fact = 1.0;
            for (int k = 0; k < 48; ++k) {
                if (k > 0) { fact *= (double)k; pw *= x * x; }
                double tk = pw / (fact * (2.0 * k + 1.0));
                esum += (k & 1) ? -tk : tk;
            }
            double erfv = 1.12837916709551257390 * esum;
            fv[j] = 0.5 * erfv / s;
        }
        double ck[10] = {};
        for (int k = 0; k < N; ++k) {
            double sum = 0.0;
            for (int j = 0; j < N; ++j) {
                double Tk = 1.0;
                if (k >= 1) {
                    double Tm2 = 1.0, Tm1 = xv[j];
                    Tk = xv[j];
                    for (int i = 2; i <= k; ++i) {
                        Tk = 2.0 * xv[j] * Tm1 - Tm2;
                        Tm2 = Tm1; Tm1 = Tk;
                    }
                }
                sum += fv[j] * Tk;
            }
            ck[k] = 2.0 * sum / N;
        }
        ck[0] *= 0.5;
        double T[10][10] = {};
        T[0][0] = 1.0;
        T[1][1] = 1.0;
        for (int k = 2; k < N; ++k)
            for (int i = 0; i < N; ++i)
                T[k][i] = 2.0 * (i > 0 ? T[k - 1][i - 1] : 0.0) - T[k - 2][i];
        double pd[10] = {};
        for (int k = 0; k < N; ++k)
            for (int i = 0; i < N; ++i)
                pd[i] += ck[k] * T[k][i];
        for (int i = 0; i < N; ++i) p[i] = (float)pd[i];
    }
};
static constexpr GeluPoly GP{};

__device__ __forceinline__ float gelu_poly(float s) {
    float c = __builtin_amdgcn_fmed3f(s, -3.0f, 3.0f);
    float t = c * c;
    float u = __builtin_fmaf(t, 0.22222222222222222f, -1.0f);
    float q = GP.p[9];
    #pragma unroll
    for (int k = 8; k >= 0; --k) q = __builtin_fmaf(q, u, GP.p[k]);
    return s * __builtin_fmaf(c, q, 0.5f);
}

// Kernel 1: projection. hx written row-major; hy written directly in the
// e-major packed layout hy4[b][e>>2][m][e&3] the cross kernel consumes.
#define PR 8
__global__ __launch_bounds__(256) void proj_kernel(
    const float* __restrict__ x0, const float* __restrict__ x,
    const float* __restrict__ y,  const float* __restrict__ W1,
    const float* __restrict__ b1, float* __restrict__ hx, float* __restrict__ hy4) {
    const int e = threadIdx.x & (DD - 1);
    const int g = threadIdx.x >> 7;
    const int nxb = (BB * NN1) / PR;
    const float* Wa = W1;
    const float* Wb = W1 + DD * DD;
    const float* Wc = W1 + 2 * DD * DD;

    if (blockIdx.x < nxb) {
        const int row0 = blockIdx.x * PR + g * (PR / 2);
        float acc0 = b1[e], acc1 = b1[e], acc2 = b1[e], acc3 = b1[e];
        #pragma unroll 4
        for (int d = 0; d < DD; ++d) {
            const float wa = Wa[d * DD + e];
            const float wb = Wb[d * DD + e];
            acc0 += x0[(row0 + 0) * DD + d] * wa + x[(row0 + 0) * DD + d] * wb;
            acc1 += x0[(row0 + 1) * DD + d] * wa + x[(row0 + 1) * DD + d] * wb;
            acc2 += x0[(row0 + 2) * DD + d] * wa + x[(row0 + 2) * DD + d] * wb;
            acc3 += x0[(row0 + 3) * DD + d] * wa + x[(row0 + 3) * DD + d] * wb;
        }
        hx[(row0 + 0) * DD + e] = acc0;
        hx[(row0 + 1) * DD + e] = acc1;
        hx[(row0 + 2) * DD + e] = acc2;
        hx[(row0 + 3) * DD + e] = acc3;
    } else {
        const int row0 = (blockIdx.x - nxb) * PR + g * (PR / 2);
        float acc[4];
        acc[0] = 0.f; acc[1] = 0.f; acc[2] = 0.f; acc[3] = 0.f;
        #pragma unroll 4
        for (int d = 0; d < DD; ++d) {
            const float wc = Wc[d * DD + e];
            acc[0] += y[(row0 + 0) * DD + d] * wc;
            acc[1] += y[(row0 + 1) * DD + d] * wc;
            acc[2] += y[(row0 + 2) * DD + d] * wc;
            acc[3] += y[(row0 + 3) * DD + d] * wc;
        }
        // hy4 index (floats): (((b*32 + e/4)*512) + m)*4 + (e&3)
        #pragma unroll
        for (int i = 0; i < 4; ++i) {
            const int r = row0 + i;           // global m-row in [0, B*NN2)
            const int bb = r >> 9;            // batch
            const int m = r & (NN2 - 1);
            hy4[((((size_t)bb * (DD / 4) + (e >> 2)) * NN2) + m) * 4 + (e & 3)] = acc[i];
        }
    }
}

// Kernel 2: LDS-free cross. Block = one n-row x 256 m's; n is block-uniform so
// hx/W2 reads are scalar (s_load); hy4 reads are coalesced dwordx4 (16 B/lane).
// out[b,n,m] = b2 + sum_e gelu(hx[n,e]+hy[m,e])*W2[e]
__global__ __launch_bounds__(256) void cross_kernel(
    const float* __restrict__ hx, const float* __restrict__ hy4,
    const float* __restrict__ W2, const float* __restrict__ b2,
    float* __restrict__ out) {
    const int tid = threadIdx.x;
    const int b = blockIdx.z;
    const int n = blockIdx.y;
    const int m = blockIdx.x * 256 + tid;

    const float* hxrow = hx + ((size_t)b * NN1 + n) * DD;
    const v4f* hyp = (const v4f*)hy4 + (size_t)b * (DD / 4) * NN2 + m;

    float acc = b2[0];
    #pragma unroll 8
    for (int e4 = 0; e4 < DD / 4; ++e4) {
        const v4f hv = hyp[(size_t)e4 * NN2];           // per-lane, coalesced 16B
        const v4f ax = *(const v4f*)&hxrow[e4 * 4];     // uniform -> s_load
        const v4f w  = *(const v4f*)&W2[e4 * 4];        // uniform -> s_load
        acc = __builtin_fmaf(gelu_poly(ax.x + hv.x), w.x, acc);
        acc = __builtin_fmaf(gelu_poly(ax.y + hv.y), w.y, acc);
        acc = __builtin_fmaf(gelu_poly(ax.z + hv.z), w.z, acc);
        acc = __builtin_fmaf(gelu_poly(ax.w + hv.w), w.w, acc);
    }

    out[((size_t)b * NN1 + n) * NN2 + m] = acc;
}

extern "C" void kernel_launch(void* const* d_in, const int* in_sizes, int n_in,
                              void* d_out, int out_size, void* d_ws, size_t ws_size,
                              hipStream_t stream) {
    const float* x0 = (const float*)d_in[0];
    const float* x  = (const float*)d_in[1];
    const float* y  = (const float*)d_in[2];
    const float* W1 = (const float*)d_in[3];
    const float* b1 = (const float*)d_in[4];
    const float* W2 = (const float*)d_in[5];
    const float* b2 = (const float*)d_in[6];
    float* out = (float*)d_out;

    float* hx  = (float*)d_ws;                  // B*N1*D floats = 512 KB
    float* hy4 = hx + (size_t)BB * NN1 * DD;    // B*N2*D floats = 512 KB, e-major packed

    const int nblocks = (BB * NN1) / PR + (BB * NN2) / PR;  // 256
    proj_kernel<<<nblocks, 256, 0, stream>>>(x0, x, y, W1, b1, hx, hy4);
    cross_kernel<<<dim3(NN2 / 256, NN1, BB), 256, 0, stream>>>(hx, hy4, W2, b2, out);
}